// Round 1
// baseline (1777.429 us; speedup 1.0000x reference)
//
#include <hip/hip_runtime.h>
#include <hip/hip_bf16.h>

#define N_ROWS 512
#define DIM    2048
#define P_ROWS 100000

#define BM 128
#define BN 128
#define BK 32
#define KT (DIM / BK)          // 64 k-iterations
#define PTILES ((P_ROWS + BN - 1) / BN)   // 782

typedef __attribute__((ext_vector_type(8))) short short8;   // 8 bf16 (4 VGPRs)
typedef __attribute__((ext_vector_type(4))) float floatx4;  // 4 fp32 acc

// ws layout (float / uint slots):
//   [0, 512)        xx[i]   = ||x_i||^2                  (float)
//   [512, 1024)     ap[i]   = d2(i, labels[i]) exact fp32 (float)
//   [1024, 1536)    gmin[i] = min d2 over j != label      (uint bits of nonneg float)

// ---------------------------------------------------------------------------
// Kernel A: per-row fp32 stats: xx, exact d2 to the label slot, init gmin=+inf
// ---------------------------------------------------------------------------
__global__ __launch_bounds__(256) void rowstats_kernel(
    const float* __restrict__ x, const float* __restrict__ feats,
    const int* __restrict__ labels, float* __restrict__ ws)
{
    const int i = blockIdx.x;
    const int t = threadIdx.x;
    const int lab = labels[i];
    const float* xr = x + (size_t)i * DIM;
    const float* fr = feats + (size_t)lab * DIM;
    float s1 = 0.f, s2 = 0.f, s3 = 0.f;
    for (int k = t; k < DIM; k += 256) {
        float a = xr[k], b = fr[k];
        s1 += a * a; s2 += b * b; s3 += a * b;
    }
    for (int off = 32; off; off >>= 1) {
        s1 += __shfl_down(s1, off);
        s2 += __shfl_down(s2, off);
        s3 += __shfl_down(s3, off);
    }
    __shared__ float r1[4], r2[4], r3[4];
    const int w = t >> 6;
    if ((t & 63) == 0) { r1[w] = s1; r2[w] = s2; r3[w] = s3; }
    __syncthreads();
    if (t == 0) {
        float a1 = r1[0] + r1[1] + r1[2] + r1[3];
        float a2 = r2[0] + r2[1] + r2[2] + r2[3];
        float a3 = r3[0] + r3[1] + r3[2] + r3[3];
        ws[i] = a1;                               // xx
        ws[N_ROWS + i] = a1 + a2 - 2.0f * a3;     // ap d2 (exact fp32)
        ((unsigned*)ws)[2 * N_ROWS + i] = 0x7F800000u;  // +inf bits
    }
}

// RNE pack of two fp32 into one dword of two bf16 (a -> low half)
__device__ inline unsigned pack2_bf16(float a, float b) {
    unsigned ua = __float_as_uint(a), ub = __float_as_uint(b);
    ua += 0x7FFFu + ((ua >> 16) & 1u);
    ub += 0x7FFFu + ((ub >> 16) & 1u);
    return (ua >> 16) | (ub & 0xFFFF0000u);
}

// ---------------------------------------------------------------------------
// Kernel B: bf16 MFMA GEMM (x · feats^T) with fused fp32->bf16 conversion,
// fused ||f_j||^2 accumulation, and per-row masked-min epilogue -> atomicMin.
// ---------------------------------------------------------------------------
#define LDSTRIDE 40   // bf16 elems per LDS row (32 + 8 pad; 80 B, 16B-aligned)

__global__ __launch_bounds__(256) void gemm_min_kernel(
    const float* __restrict__ x, const float* __restrict__ feats,
    const int* __restrict__ labels, float* __restrict__ ws)
{
    __shared__ unsigned short As[BM * LDSTRIDE];
    __shared__ unsigned short Bs[BN * LDSTRIDE];
    __shared__ float ss_lds[128 * 8];
    __shared__ float xx_s[128];
    __shared__ int   lab_s[128];
    __shared__ float yy_s[128];

    const int tid = threadIdx.x;
    const int bid = blockIdx.x;
    const int mt  = bid & 3;          // 4 m-tiles adjacent -> B-tile L2/L3 reuse
    const int pt  = bid >> 2;
    const int m0  = mt * BM;
    const int p0  = pt * BN;

    if (tid < 128) {
        xx_s[tid]  = ws[m0 + tid];
        lab_s[tid] = labels[m0 + tid];
    }

    // staging geometry: per k-iter, 4 rounds x 32 rows; thread -> (row, 4 cols)
    const int jb = tid >> 3;     // 0..31 row-in-round
    const int c8 = tid & 7;      // 0..7
    const int c0 = c8 * 4;       // float col 0..28

    bool bvalid[4];
    const float* aptr[4];
    const float* bptr[4];
    for (int r = 0; r < 4; ++r) {
        const int arow = m0 + r * 32 + jb;
        const int brow = p0 + r * 32 + jb;
        bvalid[r] = (brow < P_ROWS);
        aptr[r] = x + (size_t)arow * DIM + c0;
        bptr[r] = feats + (size_t)(bvalid[r] ? brow : 0) * DIM + c0;
    }

    // wave geometry
    const int lane = tid & 63;
    const int wid  = tid >> 6;
    const int wm   = (wid & 1) * 64;
    const int wn   = (wid >> 1) * 64;
    const int cq   = lane >> 4;   // quad 0..3
    const int cc   = lane & 15;   // col 0..15

    floatx4 acc[4][4];
    for (int mi = 0; mi < 4; ++mi)
        for (int ni = 0; ni < 4; ++ni)
            acc[mi][ni] = (floatx4){0.f, 0.f, 0.f, 0.f};
    float ssacc[4] = {0.f, 0.f, 0.f, 0.f};

    float4 ra[4], rb[4];
    for (int r = 0; r < 4; ++r) {
        ra[r] = *reinterpret_cast<const float4*>(aptr[r]);
        rb[r] = bvalid[r] ? *reinterpret_cast<const float4*>(bptr[r])
                          : make_float4(0.f, 0.f, 0.f, 0.f);
    }

    for (int kt = 0; kt < KT; ++kt) {
        __syncthreads();   // previous iter's frag reads complete
        for (int r = 0; r < 4; ++r) {
            const int base = (r * 32 + jb) * LDSTRIDE + c0;
            *(uint2*)&As[base] = make_uint2(pack2_bf16(ra[r].x, ra[r].y),
                                            pack2_bf16(ra[r].z, ra[r].w));
            *(uint2*)&Bs[base] = make_uint2(pack2_bf16(rb[r].x, rb[r].y),
                                            pack2_bf16(rb[r].z, rb[r].w));
            ssacc[r] += rb[r].x * rb[r].x + rb[r].y * rb[r].y
                      + rb[r].z * rb[r].z + rb[r].w * rb[r].w;
        }
        // prefetch next k-slice (in flight during MFMA section)
        if (kt + 1 < KT) {
            const int koff = (kt + 1) * BK;
            for (int r = 0; r < 4; ++r) {
                ra[r] = *reinterpret_cast<const float4*>(aptr[r] + koff);
                rb[r] = bvalid[r] ? *reinterpret_cast<const float4*>(bptr[r] + koff)
                                  : make_float4(0.f, 0.f, 0.f, 0.f);
            }
        }
        __syncthreads();   // LDS writes visible
        short8 bfr[4];
        for (int ni = 0; ni < 4; ++ni)
            bfr[ni] = *(const short8*)&Bs[(wn + ni * 16 + cc) * LDSTRIDE + cq * 8];
        for (int mi = 0; mi < 4; ++mi) {
            const short8 afr = *(const short8*)&As[(wm + mi * 16 + cc) * LDSTRIDE + cq * 8];
            for (int ni = 0; ni < 4; ++ni)
                acc[mi][ni] = __builtin_amdgcn_mfma_f32_16x16x32_bf16(
                    afr, bfr[ni], acc[mi][ni], 0, 0, 0);
        }
    }

    // reduce ||f_j||^2 partials -> yy_s
    __syncthreads();
    for (int r = 0; r < 4; ++r)
        ss_lds[(r * 32 + jb) * 8 + c8] = ssacc[r];
    __syncthreads();
    if (tid < 128) {
        float s = 0.f;
        for (int c = 0; c < 8; ++c) s += ss_lds[tid * 8 + c];
        yy_s[tid] = s;
    }
    __syncthreads();

    // epilogue: d2 = xx + yy - 2*dot; mask label & OOB; per-row min -> atomicMin
    unsigned* gmin = (unsigned*)ws + 2 * N_ROWS;
    for (int mi = 0; mi < 4; ++mi) {
        for (int rg = 0; rg < 4; ++rg) {
            const int li  = wm + mi * 16 + cq * 4 + rg;   // local row (C/D layout)
            const float xxv = xx_s[li];
            const int   lv  = lab_s[li];
            float vmin = __uint_as_float(0x7F800000u);    // +inf
            for (int ni = 0; ni < 4; ++ni) {
                const int jl = wn + ni * 16 + cc;
                const int jg = p0 + jl;
                float d2 = xxv + yy_s[jl] - 2.0f * acc[mi][ni][rg];
                if (jg >= P_ROWS || jg == lv) d2 = __uint_as_float(0x7F800000u);
                vmin = fminf(vmin, d2);
            }
            for (int off = 1; off <= 8; off <<= 1)
                vmin = fminf(vmin, __shfl_xor(vmin, off));
            if (cc == 0) {
                vmin = fmaxf(vmin, 0.0f);   // nonneg => uint order == float order
                atomicMin(&gmin[m0 + li], __float_as_uint(vmin));
            }
        }
    }
}

// ---------------------------------------------------------------------------
// Kernel C: loss = mean(softplus(ap - an))
// ---------------------------------------------------------------------------
__global__ __launch_bounds__(512) void loss_kernel(
    const float* __restrict__ ws, float* __restrict__ out)
{
    const int t = threadIdx.x;
    const float ap2 = ws[N_ROWS + t];
    const float an2 = __uint_as_float(((const unsigned*)ws)[2 * N_ROWS + t]);
    const float ap = sqrtf(fmaxf(ap2, 1e-12f));
    const float an = sqrtf(fmaxf(an2, 1e-12f));
    const float z  = ap - an;                       // = -(an - ap)
    float sp = fmaxf(z, 0.0f) + log1pf(expf(-fabsf(z)));
    for (int off = 32; off; off >>= 1) sp += __shfl_down(sp, off);
    __shared__ float r[8];
    if ((t & 63) == 0) r[t >> 6] = sp;
    __syncthreads();
    if (t == 0) {
        float s = 0.f;
        for (int w = 0; w < 8; ++w) s += r[w];
        out[0] = s / (float)N_ROWS;
    }
}

extern "C" void kernel_launch(void* const* d_in, const int* in_sizes, int n_in,
                              void* d_out, int out_size, void* d_ws, size_t ws_size,
                              hipStream_t stream) {
    const float* x      = (const float*)d_in[0];
    const float* feats  = (const float*)d_in[1];
    const int*   labels = (const int*)d_in[2];
    float* ws  = (float*)d_ws;
    float* out = (float*)d_out;

    rowstats_kernel<<<N_ROWS, 256, 0, stream>>>(x, feats, labels, ws);
    gemm_min_kernel<<<4 * PTILES, 256, 0, stream>>>(x, feats, labels, ws);
    loss_kernel<<<1, 512, 0, stream>>>(ws, out);
}